// Round 5
// baseline (1098.691 us; speedup 1.0000x reference)
//
#include <hip/hip_runtime.h>
#include <stdint.h>

#define NROWS 204800
#define NBLK_Y 1600   // NROWS/128 (gemm blocks per input)
#define NBLK_F 3200   // NROWS/64  (k_fused grid)
#define GRP 2048
#define NPG 100

typedef __attribute__((ext_vector_type(4))) float f32x4;
typedef __attribute__((ext_vector_type(8))) short bf16x8;
typedef __attribute__((ext_vector_type(4))) short bf16x4;

__device__ __forceinline__ unsigned bcu(float f){ union{float f;unsigned u;}c; c.f=f; return c.u; }
__device__ __forceinline__ float bcf(unsigned u){ union{unsigned u;float f;}c; c.u=u; return c.f; }
__device__ __forceinline__ short f2bf_rne(float f){ unsigned u=bcu(f); unsigned r=(u+0x7fffu+((u>>16)&1u))>>16; return (short)r; }
// pack two floats -> two bf16 (truncation) in one v_perm
__device__ __forceinline__ unsigned pk_trunc(float lo, float hi){
  return __builtin_amdgcn_perm(bcu(hi), bcu(lo), 0x07060302u);
}
__device__ __forceinline__ f32x4 mfma16(bf16x8 a, bf16x8 b, f32x4 c){
  return __builtin_amdgcn_mfma_f32_16x16x32_bf16(a, b, c, 0, 0, 0);
}
#define BFLY16(v) { v += __shfl_xor(v,1); v += __shfl_xor(v,2); v += __shfl_xor(v,4); v += __shfl_xor(v,8); }

// ---------------- cast p0_W / p1_W to bf16 ----------------
__global__ void k_cast_w(const float* __restrict__ w0, const float* __restrict__ w1,
                         short* __restrict__ out){
  int t = blockIdx.x*256 + threadIdx.x;     // 32768 threads
  const float* src = (t < 16384) ? w0 : w1;
  int base = (t & 16383) * 4;
  f32x4 v = *(const f32x4*)(src + base);
  bf16x4 o; o[0]=f2bf_rne(v[0]); o[1]=f2bf_rne(v[1]); o[2]=f2bf_rne(v[2]); o[3]=f2bf_rne(v[3]);
  *(bf16x4*)(out + ((t<16384)?0:65536) + base) = o;
}

// ---------------- y = x @ W^T + b, bf16 store, col stats ----------------
// v5: x-tile staged in LDS as bf16 (XOR-swizzled). Per tile mt, x frags are
// RE-READ from LDS (no long-lived VGPR arrays -> nothing for RA to spill;
// v2-v4 proved the allocator spills any 64+ reg resident array). Only the
// W-frag double buffer (32 regs) + acc (8) are loop-carried.
// asm-touch on the LDS base addr per tile defeats CSE of the (identical)
// per-tile LDS reads, which would otherwise recreate the resident array.
__global__ __attribute__((amdgpu_waves_per_eu(2, 2))) void __launch_bounds__(256)
k_gemm_y(const float* __restrict__ x0, const float* __restrict__ x1,
         const short* __restrict__ Wb,
         const float* __restrict__ b0p, const float* __restrict__ b1p,
         short* __restrict__ y0, short* __restrict__ y1,
         float* __restrict__ stats){
  __shared__ __align__(16) short xs[32768];   // [128][256] bf16, swizzled (64KB)
  __shared__ float st_sh[4][256][2];          // 8KB
  int bid = blockIdx.x;
  int which = (bid >= NBLK_Y) ? 1 : 0;
  const float* __restrict__ X = which ? x1 : x0;
  short* __restrict__ Y = which ? y1 : y0;
  const short* __restrict__ W = Wb + which*65536;
  const float* __restrict__ bias = which ? b1p : b0p;
  int n0 = (which ? bid - NBLK_Y : bid) * 128;
  int t = threadIdx.x, lane = t & 63, w = t >> 6;
  int l15 = lane & 15, q = lane >> 4;

  // ---- stage x-tile -> LDS bf16, swizzled. wave w fills rows s*4+w,
  // each step: 64 lanes x 16B f32 = one full 1KB row (perfect coalescing).
  #pragma unroll
  for (int s=0; s<32; s++){
    int row = s*4 + w;
    f32x4 v = *(const f32x4*)(X + (n0+row)*256 + (lane<<2));
    int2 pk2; pk2.x=(int)pk_trunc(v[0],v[1]); pk2.y=(int)pk_trunc(v[2],v[3]);
    int byte = (row<<9) + (lane<<3);
    *(int2*)((char*)xs + (byte ^ ((row&7)<<4))) = pk2;
  }

  const short* wrow = W + l15*256;   // A row base for this lane
  bf16x8 wfA[4], wfB[4];
  #pragma unroll
  for (int ks=0; ks<4; ks++)
    wfA[ks] = *(const bf16x8*)(wrow + ks*32 + q*8);

  int pA = (w*32 + l15)*512 + q*16;   // byte base, row-group 0
  int pB = pA + 16*512;               // row-group 1
  const int swzC = (l15 & 7) << 4;

  short* yo0 = Y + (n0 + w*32 + l15)*256 + q*4;
  short* yo1 = yo0 + 16*256;

  __syncthreads();

  #pragma unroll
  for (int mt=0; mt<16; mt++){
    // issue wfB = W[mt] ks4..7 (consumed after first 8 MFMAs)
    #pragma unroll
    for (int ks=0; ks<4; ks++)
      wfB[ks] = *(const bf16x8*)(wrow + mt*4096 + (ks+4)*32 + q*8);
    // opaque-touch the LDS bases: blocks CSE/hoist of the per-tile reads
    asm volatile("" : "+v"(pA), "+v"(pB));
    bf16x8 xg0[8], xg1[8];
    #pragma unroll
    for (int ks=0; ks<8; ks++){
      xg0[ks] = *(const bf16x8*)((const char*)xs + ((pA + ks*64) ^ swzC));
      xg1[ks] = *(const bf16x8*)((const char*)xs + ((pB + ks*64) ^ swzC));
    }
    f32x4 acc0 = f32x4{0,0,0,0}, acc1 = f32x4{0,0,0,0};
    #pragma unroll
    for (int ks=0; ks<4; ks++){
      acc0 = mfma16(wfA[ks], xg0[ks], acc0);
      acc1 = mfma16(wfA[ks], xg1[ks], acc1);
    }
    if (mt < 15){
      #pragma unroll
      for (int ks=0; ks<4; ks++)
        wfA[ks] = *(const bf16x8*)(wrow + (mt+1)*4096 + ks*32 + q*8);
    }
    #pragma unroll
    for (int ks=0; ks<4; ks++){
      acc0 = mfma16(wfB[ks], xg0[ks+4], acc0);
      acc1 = mfma16(wfB[ks], xg1[ks+4], acc1);
    }
    // epilogue for tile mt: bias, bf16 store, per-column stats
    f32x4 bb = *(const f32x4*)(bias + mt*16 + q*4);
    f32x4 v0 = acc0 + bb;
    f32x4 v1 = acc1 + bb;
    int2 s0v; s0v.x=(int)pk_trunc(v0[0],v0[1]); s0v.y=(int)pk_trunc(v0[2],v0[3]);
    *(int2*)(yo0 + mt*16) = s0v;
    int2 s1v; s1v.x=(int)pk_trunc(v1[0],v1[1]); s1v.y=(int)pk_trunc(v1[2],v1[3]);
    *(int2*)(yo1 + mt*16) = s1v;
    float sa0=v0[0]+v1[0], sa1=v0[1]+v1[1], sa2=v0[2]+v1[2], sa3=v0[3]+v1[3];
    float qa0=v0[0]*v0[0]+v1[0]*v1[0], qa1=v0[1]*v0[1]+v1[1]*v1[1];
    float qa2=v0[2]*v0[2]+v1[2]*v1[2], qa3=v0[3]*v0[3]+v1[3]*v1[3];
    BFLY16(sa0); BFLY16(sa1); BFLY16(sa2); BFLY16(sa3);
    BFLY16(qa0); BFLY16(qa1); BFLY16(qa2); BFLY16(qa3);
    if (l15 == 0){
      int c0 = mt*16 + q*4;
      st_sh[w][c0+0][0]=sa0; st_sh[w][c0+0][1]=qa0;
      st_sh[w][c0+1][0]=sa1; st_sh[w][c0+1][1]=qa1;
      st_sh[w][c0+2][0]=sa2; st_sh[w][c0+2][1]=qa2;
      st_sh[w][c0+3][0]=sa3; st_sh[w][c0+3][1]=qa3;
    }
  }
  __syncthreads();
  {
    float ss = st_sh[0][t][0]+st_sh[1][t][0]+st_sh[2][t][0]+st_sh[3][t][0];
    float qq = st_sh[0][t][1]+st_sh[1][t][1]+st_sh[2][t][1]+st_sh[3][t][1];
    int rep = bid & 7;
    atomicAdd(&stats[rep*1024 + which*512 + t], ss);
    atomicAdd(&stats[rep*1024 + which*512 + 256 + t], qq);
  }
}

// ---------------- small precompute: BN params, q, qk, cv, cs, wfin, cfin ----------------
__global__ void k_small(const float* __restrict__ inW, const float* __restrict__ inB,
                        const float* __restrict__ mergeB,
                        const float* __restrict__ g0, const float* __restrict__ be0,
                        const float* __restrict__ g1, const float* __restrict__ be1,
                        const float* __restrict__ outW, const float* __restrict__ outB,
                        const float* __restrict__ rout, const float* __restrict__ routB,
                        const float* __restrict__ stats,
                        float* __restrict__ prm, float* __restrict__ qk){
  __shared__ float qv_sh[256], ck_sh[256];
  int t = threadIdx.x;
  const float invN = 1.0f/(float)NROWS;
  float s0=0, sq0=0, s1=0, sq1=0;
  for (int r=0;r<8;r++){
    s0  += stats[r*1024 + t];       sq0 += stats[r*1024 + 256 + t];
    s1  += stats[r*1024 + 512 + t]; sq1 += stats[r*1024 + 768 + t];
  }
  {
    float mu = s0*invN, var = sq0*invN - mu*mu;
    float rs = rsqrtf(var + 1e-5f);
    float a = g0[t]*rs;
    prm[t] = a; prm[512+t] = be0[t] - mu*a;
  }
  {
    float mu = s1*invN, var = sq1*invN - mu*mu;
    float rs = rsqrtf(var + 1e-5f);
    float a = g1[t]*rs;
    prm[256+t] = a; prm[768+t] = be1[t] - mu*a;
  }
  // qvec
  float qs = inB[t];
  for (int k=0;k<256;k++) qs += inW[t*256 + k];
  qv_sh[t] = qs * 0.17677669529663689f;  // 1/sqrt(32)
  // ck
  float cks = inB[256+t];
  for (int m=0;m<256;m++) cks += mergeB[m] * inW[(256+t)*256 + m];
  ck_sh[t] = cks;
  // cv
  float cvs = inB[512+t];
  for (int m=0;m<256;m++) cvs += mergeB[m] * inW[(512+t)*256 + m];
  prm[1024+t] = cvs;
  // wfin
  float wf = 0;
  for (int m=0;m<256;m++) wf += rout[m] * outW[m*256 + t];
  prm[1288+t] = wf;
  __syncthreads();
  // qk[h][m]
  for (int r=0;r<8;r++){
    int idx = r*256 + t; int h = idx>>8, m = idx&255;
    float s = 0;
    for (int d=0;d<32;d++) s += qv_sh[h*32+d] * inW[(256 + h*32 + d)*256 + m];
    qk[h*256+m] = s;
  }
  if (t < 8){
    float cs_ = 0;
    for (int d=0;d<32;d++) cs_ += qv_sh[t*32+d]*ck_sh[t*32+d];
    prm[1280+t] = cs_;
  }
  if (t == 0){
    float cf = routB[0];
    for (int m=0;m<256;m++) cf += rout[m]*outB[m];
    prm[1544] = cf;
  }
}

// ---------------- Wall[c][j]: c<256 -> merge^T Wv^T ; c in 256..263 -> score cols ----------------
__global__ void k_wall(const float* __restrict__ inW, const float* __restrict__ mergeW,
                       const float* __restrict__ qk, short* __restrict__ Wall){
  int c = blockIdx.x; int t = threadIdx.x;  // 272 blocks x 256 threads
  if (c >= 264){
    Wall[c*512 + t] = 0; Wall[c*512 + 256 + t] = 0; return;
  }
  const float* src = (c < 256) ? (inW + (512+c)*256) : (qk + (c-256)*256);
  float a0=0, a1=0;
  for (int m=0;m<256;m++){
    float wm = src[m];
    a0 += wm * mergeW[m*512 + t];
    a1 += wm * mergeW[m*512 + 256 + t];
  }
  Wall[c*512 + t]       = f2bf_rne(a0);
  Wall[c*512 + 256 + t] = f2bf_rne(a1);
}

// ---------------- fused BN+relu -> (v|scores) GEMM -> segment softmax-pool ----------------
// v5: same LDS-staging structure as k_gemm_y. BN+relu applied at fill time
// (coefs are per-lane constants -> 16 regs). 64 rows/block, 16 rows/wave.
// h-tile [64][512] bf16 swizzled in LDS; Wall frags double-buffered in regs.
__global__ __attribute__((amdgpu_waves_per_eu(2, 2))) void __launch_bounds__(256)
k_fused(const short* __restrict__ y0, const short* __restrict__ y1,
        const short* __restrict__ Wall, const float* __restrict__ prm,
        float* __restrict__ num, float* __restrict__ den){
  __shared__ __align__(16) short xs[32768];   // [64][512] bf16, swizzled (64KB)
  int t = threadIdx.x, lane = t & 63, w = t >> 6;
  int l15 = lane & 15, q = lane >> 4;
  int n0 = blockIdx.x * 64;

  // per-lane BN coefs for the 8 columns this lane stages (fixed per lane)
  int j0 = (lane & 31)*8 + ((lane >> 5) << 8);
  f32x4 paL = *(const f32x4*)(prm + j0);
  f32x4 paH = *(const f32x4*)(prm + j0 + 4);
  f32x4 pbL = *(const f32x4*)(prm + 512 + j0);
  f32x4 pbH = *(const f32x4*)(prm + 512 + j0 + 4);
  f32x4 csv = *(const f32x4*)(prm + 1280 + q*4);   // head consts (used q<2)

  const short* wbase = Wall + l15*512;
  bf16x8 wfA[8], wfB[8];
  #pragma unroll
  for (int ks=0; ks<8; ks++)
    wfA[ks] = *(const bf16x8*)(wbase + 16*8192 + ks*32 + q*8);

  // ---- stage h-tile: row = s*4+w; lanes<32 from y0, lanes>=32 from y1 ----
  const short* ysrc = (lane < 32) ? y0 : y1;
  #pragma unroll
  for (int s=0; s<16; s++){
    int row = s*4 + w;
    int4 raw = *(const int4*)(ysrc + (n0+row)*256 + (lane&31)*8);
    unsigned r0=(unsigned)raw.x, r1=(unsigned)raw.y, r2=(unsigned)raw.z, r3=(unsigned)raw.w;
    float h0 = fmaxf(fmaf(bcf(r0<<16),         paL[0], pbL[0]), 0.f);
    float h1 = fmaxf(fmaf(bcf(r0&0xffff0000u), paL[1], pbL[1]), 0.f);
    float h2 = fmaxf(fmaf(bcf(r1<<16),         paL[2], pbL[2]), 0.f);
    float h3 = fmaxf(fmaf(bcf(r1&0xffff0000u), paL[3], pbL[3]), 0.f);
    float h4 = fmaxf(fmaf(bcf(r2<<16),         paH[0], pbH[0]), 0.f);
    float h5 = fmaxf(fmaf(bcf(r2&0xffff0000u), paH[1], pbH[1]), 0.f);
    float h6 = fmaxf(fmaf(bcf(r3<<16),         paH[2], pbH[2]), 0.f);
    float h7 = fmaxf(fmaf(bcf(r3&0xffff0000u), paH[3], pbH[3]), 0.f);
    int4 pk4; pk4.x=(int)pk_trunc(h0,h1); pk4.y=(int)pk_trunc(h2,h3);
              pk4.z=(int)pk_trunc(h4,h5); pk4.w=(int)pk_trunc(h6,h7);
    int byte = (row<<10) + ((lane&31)<<4) + ((lane>>5)<<9);
    *(int4*)((char*)xs + (byte ^ ((row&7)<<4))) = pk4;
  }
  __syncthreads();

  int pA = (w*16 + l15)*1024 + q*16;
  const int swzC = (l15 & 7) << 4;
  int tb = n0 + w*16;
  int sg = tb/100; int brow = (sg+1)*100 - tb; bool split = brow < 16;
  float e0[4];

  // tile order: 16 (scores), then 0..15 (v tiles)
  #pragma unroll
  for (int idx=0; idx<17; idx++){
    const int T = (idx==0) ? 16 : (idx-1);
    #pragma unroll
    for (int ks=0; ks<8; ks++)
      wfB[ks] = *(const bf16x8*)(wbase + T*8192 + (ks+8)*32 + q*8);
    asm volatile("" : "+v"(pA));
    bf16x8 xg[16];
    #pragma unroll
    for (int ks=0; ks<16; ks++)
      xg[ks] = *(const bf16x8*)((const char*)xs + ((pA + ks*64) ^ swzC));
    f32x4 accA = f32x4{0,0,0,0}, accB = f32x4{0,0,0,0};
    #pragma unroll
    for (int ks=0; ks<8; ks++) accA = mfma16(wfA[ks], xg[ks], accA);
    if (idx < 16){
      #pragma unroll
      for (int ks=0; ks<8; ks++)
        wfA[ks] = *(const bf16x8*)(wbase + idx*8192 + ks*32 + q*8);
    }
    #pragma unroll
    for (int ks=0; ks<8; ks++) accB = mfma16(wfB[ks], xg[ks+8], accB);
    f32x4 acc = accA + accB;

    if (T == 16){
      // ---- scores epilogue: e, den ----
      #pragma unroll
      for (int i=0;i<4;i++)
        e0[i] = (q<2) ? __expf(acc[i] + csv[i]) : 0.f;
      float d0[4], d1[4];
      #pragma unroll
      for (int i=0;i<4;i++){ d0[i] = (l15 < brow) ? e0[i] : 0.f; d1[i] = e0[i] - d0[i]; }
      BFLY16(d0[0]); BFLY16(d0[1]); BFLY16(d0[2]); BFLY16(d0[3]);
      if (split){ BFLY16(d1[0]); BFLY16(d1[1]); BFLY16(d1[2]); BFLY16(d1[3]); }
      if (l15==0 && q<2){
        #pragma unroll
        for (int i=0;i<4;i++) atomicAdd(&den[sg*8 + q*4 + i], d0[i]);
        if (split){
          #pragma unroll
          for (int i=0;i<4;i++) atomicAdd(&den[(sg+1)*8 + q*4 + i], d1[i]);
        }
      }
    } else {
      // ---- v-tile epilogue: weighted pooling into num ----
      const int h = T>>1, hq = h>>2, hi = h&3;
      f32x4 cvv = *(const f32x4*)(prm + 1024 + T*16 + q*4);
      float eb = __shfl(e0[hi], hq*16 + l15, 64);
      float pv0[4], pv1[4];
      #pragma unroll
      for (int i=0;i<4;i++){
        float wv = (acc[i] + cvv[i]) * eb;
        pv0[i] = (l15 < brow) ? wv : 0.f; pv1[i] = wv - pv0[i];
      }
      BFLY16(pv0[0]); BFLY16(pv0[1]); BFLY16(pv0[2]); BFLY16(pv0[3]);
      if (split){ BFLY16(pv1[0]); BFLY16(pv1[1]); BFLY16(pv1[2]); BFLY16(pv1[3]); }
      if (l15==0){
        int c0 = T*16 + q*4;
        #pragma unroll
        for (int i=0;i<4;i++) atomicAdd(&num[sg*256 + c0 + i], pv0[i]);
        if (split){
          #pragma unroll
          for (int i=0;i<4;i++) atomicAdd(&num[(sg+1)*256 + c0 + i], pv1[i]);
        }
      }
    }
  }
}

// ---------------- final: out[g] = tanh(sum_c num/den * wfin + cfin) ----------------
__global__ void k_out(const float* __restrict__ num, const float* __restrict__ den,
                      const float* __restrict__ prm, float* __restrict__ out){
  int g = blockIdx.x; int lane = threadIdx.x; // 64
  f32x4 nm = *(const f32x4*)(num + g*256 + lane*4);
  f32x4 wf = *(const f32x4*)(prm + 1288 + lane*4);
  float dh = den[g*8 + (lane>>3)];
  float v = (nm[0]*wf[0] + nm[1]*wf[1] + nm[2]*wf[2] + nm[3]*wf[3]) / dh;
  v += __shfl_xor(v,1); v += __shfl_xor(v,2); v += __shfl_xor(v,4);
  v += __shfl_xor(v,8); v += __shfl_xor(v,16); v += __shfl_xor(v,32);
  if (lane==0) out[g] = tanhf(v + prm[1544]);
}

extern "C" void kernel_launch(void* const* d_in, const int* in_sizes, int n_in,
                              void* d_out, int out_size, void* d_ws, size_t ws_size,
                              hipStream_t stream){
  const float* x0      = (const float*)d_in[0];
  const float* x1      = (const float*)d_in[1];
  const float* p0_W    = (const float*)d_in[3];
  const float* p0_b    = (const float*)d_in[4];
  const float* p0_g    = (const float*)d_in[5];
  const float* p0_beta = (const float*)d_in[6];
  const float* p1_W    = (const float*)d_in[7];
  const float* p1_b    = (const float*)d_in[8];
  const float* p1_g    = (const float*)d_in[9];
  const float* p1_beta = (const float*)d_in[10];
  const float* merge_W = (const float*)d_in[11];
  const float* merge_b = (const float*)d_in[12];
  const float* inp_W   = (const float*)d_in[13];
  const float* inp_b   = (const float*)d_in[14];
  const float* out_W   = (const float*)d_in[15];
  const float* out_b   = (const float*)d_in[16];
  const float* ro_W    = (const float*)d_in[17];
  const float* ro_b    = (const float*)d_in[18];
  float* outp = (float*)d_out;

  char* ws = (char*)d_ws;
  short* y0w   = (short*)(ws);
  short* y1w   = (short*)(ws + 104857600);
  short* Wb    = (short*)(ws + 209715200);
  short* Wall  = (short*)(ws + 209977344);
  float* stats = (float*)(ws + 210255872);
  float* num   = (float*)(ws + 210288640);
  float* den   = (float*)(ws + 212385792);
  float* prm   = (float*)(ws + 212451328);
  float* qk    = (float*)(ws + 212459520);

  hipMemsetAsync(ws + 210255872, 0, 2195456, stream);   // stats + num + den

  k_cast_w<<<dim3(128), dim3(256), 0, stream>>>(p0_W, p1_W, Wb);
  k_gemm_y<<<dim3(2*NBLK_Y), dim3(256), 0, stream>>>(x0, x1, Wb, p0_b, p1_b, y0w, y1w, stats);
  k_small<<<dim3(1), dim3(256), 0, stream>>>(inp_W, inp_b, merge_b, p0_g, p0_beta, p1_g, p1_beta,
                                             out_W, out_b, ro_W, ro_b, stats, prm, qk);
  k_wall<<<dim3(272), dim3(256), 0, stream>>>(inp_W, merge_W, qk, Wall);
  k_fused<<<dim3(NBLK_F), dim3(256), 0, stream>>>(y0w, y1w, Wall, prm, num, den);
  k_out<<<dim3(GRP), dim3(64), 0, stream>>>(num, den, prm, outp);
}

// Round 6
// 961.859 us; speedup vs baseline: 1.1423x; 1.1423x over previous
//
#include <hip/hip_runtime.h>
#include <stdint.h>

#define NROWS 204800
#define NBLK_Y 1600   // gemm blocks per input (128 rows each)
#define NBLK_F 800    // fused blocks (256 rows each)
#define GRP 2048

typedef __attribute__((ext_vector_type(4))) float f32x4;
typedef __attribute__((ext_vector_type(8))) short bf16x8;

__device__ __forceinline__ unsigned bcu(float f){ union{float f;unsigned u;}c; c.f=f; return c.u; }
__device__ __forceinline__ float bcf(unsigned u){ union{unsigned u;float f;}c; c.u=u; return c.f; }
__device__ __forceinline__ short f2bf_rne(float f){ unsigned u=bcu(f); unsigned r=(u+0x7fffu+((u>>16)&1u))>>16; return (short)r; }
__device__ __forceinline__ unsigned pk_trunc(float lo, float hi){
  return __builtin_amdgcn_perm(bcu(hi), bcu(lo), 0x07060302u);
}
__device__ __forceinline__ f32x4 mfma16(bf16x8 a, bf16x8 b, f32x4 c){
  return __builtin_amdgcn_mfma_f32_16x16x32_bf16(a, b, c, 0, 0, 0);
}
// global -> LDS direct copy, 16B per lane. LDS dest = wave-uniform base + lane*16.
__device__ __forceinline__ void gl16(const void* g, void* l){
  __builtin_amdgcn_global_load_lds(
      (const __attribute__((address_space(1))) void*)g,
      (__attribute__((address_space(3))) void*)l, 16, 0, 0);
}
#define BFLY16(v) { v += __shfl_xor(v,1); v += __shfl_xor(v,2); v += __shfl_xor(v,4); v += __shfl_xor(v,8); }

// ---------------- cast W -> bf16, PRE-TILED/PRE-SWIZZLED for gload_lds ----------------
// Layout: [which][step s(8)][16KB chunk]; chunk unit lu = (col>>1)*8 + ((((col&1)<<2)|q) ^ (col&7))
// holds W[col][k = s*32 + q*8 .. +7]. A straight linear copy of the chunk into LDS then gives
// conflict-free swizzled reads at byte (col*64 + q*16) ^ ((col&7)<<4).
__global__ void k_cast_w(const float* __restrict__ w0, const float* __restrict__ w1,
                         short* __restrict__ out){
  int g = blockIdx.x*256 + threadIdx.x;     // 16384 threads
  int which = g >> 13, r = g & 8191;
  int col = r >> 5, s = (r >> 2) & 7, q = r & 3;
  const float* src = (which ? w1 : w0) + col*256 + s*32 + q*8;
  f32x4 a = *(const f32x4*)src;
  f32x4 b = *(const f32x4*)(src + 4);
  bf16x8 o;
  o[0]=f2bf_rne(a[0]); o[1]=f2bf_rne(a[1]); o[2]=f2bf_rne(a[2]); o[3]=f2bf_rne(a[3]);
  o[4]=f2bf_rne(b[0]); o[5]=f2bf_rne(b[1]); o[6]=f2bf_rne(b[2]); o[7]=f2bf_rne(b[3]);
  int lu = ((col>>1)<<3) + ((((col&1)<<2) | q) ^ (col&7));
  *(bf16x8*)(out + which*65536 + s*8192 + lu*8) = o;
}

// ---------------- y = x @ W^T + b : 2-phase LDS GEMM (m97/T3-minimum structure) ----------------
// Block: 128 rows x 256 cols, K=256, BK=32 (8 steps), 4 waves.
// LDS: x f32 tile [128][32] (16KB) dbuf + W bf16 tile [256][32] (16KB) dbuf = 64KB (+8KB stats).
// ALL staging via global_load_lds (8 x 16B in flight per thread -> ~64KB/CU in flight:
// fixes the Little's-law 2.4TB/s ceiling of v1-v5's VGPR-destination loads).
// x source pre-swizzled per lane (unit ^= row&7); W copied from pre-tiled Wb.
__global__ void __launch_bounds__(256)
k_gemm_y(const float* __restrict__ x0, const float* __restrict__ x1,
         const short* __restrict__ Wb,
         const float* __restrict__ b0p, const float* __restrict__ b1p,
         short* __restrict__ y0, short* __restrict__ y1,
         float* __restrict__ stats){
  __shared__ __align__(16) char lds[65536];
  __shared__ float st_sh[4][256][2];
  int bid = blockIdx.x;
  int which = (bid >= NBLK_Y) ? 1 : 0;
  const float* __restrict__ X = which ? x1 : x0;
  short* __restrict__ Y = which ? y1 : y0;
  const float* __restrict__ bias = which ? b1p : b0p;
  int n0 = (which ? bid - NBLK_Y : bid) * 128;
  int t = threadIdx.x, lane = t & 63, w = t >> 6;
  int l15 = lane & 15, q = lane >> 4;
  const char* Wg = (const char*)Wb + (size_t)which*131072;

  f32x4 acc[16][2];
  #pragma unroll
  for (int mt=0; mt<16; mt++){ acc[mt][0]=f32x4{0,0,0,0}; acc[mt][1]=f32x4{0,0,0,0}; }

  auto stage = [&](int s_, int b_){
    #pragma unroll
    for (int i=0;i<4;i++){
      int uu = i*256 + t, row = uu>>3, cu = uu&7;
      gl16((const char*)X + ((size_t)(n0+row)<<10) + (s_<<7) + ((cu ^ (row&7))<<4),
           lds + b_*16384 + ((i*256 + (w<<6))<<4));
    }
    #pragma unroll
    for (int i=0;i<4;i++)
      gl16(Wg + (s_<<14) + ((i*256 + t)<<4),
           lds + 32768 + b_*16384 + ((i*256 + (w<<6))<<4));
  };

  auto kstep = [&](int b_){
    int swz = (l15&7)<<4;
    bf16x8 hx0, hx1;
    {
      const char* p = lds + b_*16384;
      int rowl = (w<<5) + l15;
      f32x4 f0 = *(const f32x4*)(p + (((rowl<<7) + (q<<5)) ^ swz));
      f32x4 f1 = *(const f32x4*)(p + (((rowl<<7) + (q<<5) + 16) ^ swz));
      int4 pk4; pk4.x=(int)pk_trunc(f0[0],f0[1]); pk4.y=(int)pk_trunc(f0[2],f0[3]);
                pk4.z=(int)pk_trunc(f1[0],f1[1]); pk4.w=(int)pk_trunc(f1[2],f1[3]);
      hx0 = __builtin_bit_cast(bf16x8, pk4);
      rowl += 16;
      f32x4 g0 = *(const f32x4*)(p + (((rowl<<7) + (q<<5)) ^ swz));
      f32x4 g1 = *(const f32x4*)(p + (((rowl<<7) + (q<<5) + 16) ^ swz));
      pk4.x=(int)pk_trunc(g0[0],g0[1]); pk4.y=(int)pk_trunc(g0[2],g0[3]);
      pk4.z=(int)pk_trunc(g1[0],g1[1]); pk4.w=(int)pk_trunc(g1[2],g1[3]);
      hx1 = __builtin_bit_cast(bf16x8, pk4);
    }
    const char* wp = lds + 32768 + b_*16384;
    #pragma unroll
    for (int mt=0; mt<16; mt++){
      int col = (mt<<4) + l15;
      bf16x8 wf = *(const bf16x8*)(wp + (((col<<6) + (q<<4)) ^ swz));
      acc[mt][0] = mfma16(wf, hx0, acc[mt][0]);
      acc[mt][1] = mfma16(wf, hx1, acc[mt][1]);
    }
  };

  stage(0, 0);
  __syncthreads();
  int buf = 0;
  #pragma unroll
  for (int s=0; s<8; s++){
    if (s < 7) stage(s+1, buf^1);
    kstep(buf);
    __syncthreads();
    buf ^= 1;
  }

  // epilogue: bias, bf16 store, per-column stats (v1-verified layout)
  int nb = n0 + (w<<5);
  short* yo0 = Y + (size_t)(nb + l15)*256 + q*4;
  short* yo1 = yo0 + 16*256;
  #pragma unroll
  for (int mt=0; mt<16; mt++){
    f32x4 bb = *(const f32x4*)(bias + mt*16 + q*4);
    f32x4 v0 = acc[mt][0] + bb;
    f32x4 v1 = acc[mt][1] + bb;
    int2 s0v; s0v.x=(int)pk_trunc(v0[0],v0[1]); s0v.y=(int)pk_trunc(v0[2],v0[3]);
    *(int2*)(yo0 + mt*16) = s0v;
    int2 s1v; s1v.x=(int)pk_trunc(v1[0],v1[1]); s1v.y=(int)pk_trunc(v1[2],v1[3]);
    *(int2*)(yo1 + mt*16) = s1v;
    float sa0=v0[0]+v1[0], sa1=v0[1]+v1[1], sa2=v0[2]+v1[2], sa3=v0[3]+v1[3];
    float qa0=v0[0]*v0[0]+v1[0]*v1[0], qa1=v0[1]*v0[1]+v1[1]*v1[1];
    float qa2=v0[2]*v0[2]+v1[2]*v1[2], qa3=v0[3]*v0[3]+v1[3]*v1[3];
    BFLY16(sa0); BFLY16(sa1); BFLY16(sa2); BFLY16(sa3);
    BFLY16(qa0); BFLY16(qa1); BFLY16(qa2); BFLY16(qa3);
    if (l15 == 0){
      int c0 = mt*16 + q*4;
      st_sh[w][c0+0][0]=sa0; st_sh[w][c0+0][1]=qa0;
      st_sh[w][c0+1][0]=sa1; st_sh[w][c0+1][1]=qa1;
      st_sh[w][c0+2][0]=sa2; st_sh[w][c0+2][1]=qa2;
      st_sh[w][c0+3][0]=sa3; st_sh[w][c0+3][1]=qa3;
    }
  }
  __syncthreads();
  {
    float ss = st_sh[0][t][0]+st_sh[1][t][0]+st_sh[2][t][0]+st_sh[3][t][0];
    float qq = st_sh[0][t][1]+st_sh[1][t][1]+st_sh[2][t][1]+st_sh[3][t][1];
    int rep = bid & 7;
    atomicAdd(&stats[rep*1024 + which*512 + t], ss);
    atomicAdd(&stats[rep*1024 + which*512 + 256 + t], qq);
  }
}

// ---------------- small precompute (unchanged) ----------------
__global__ void k_small(const float* __restrict__ inW, const float* __restrict__ inB,
                        const float* __restrict__ mergeB,
                        const float* __restrict__ g0, const float* __restrict__ be0,
                        const float* __restrict__ g1, const float* __restrict__ be1,
                        const float* __restrict__ outW, const float* __restrict__ outB,
                        const float* __restrict__ rout, const float* __restrict__ routB,
                        const float* __restrict__ stats,
                        float* __restrict__ prm, float* __restrict__ qk){
  __shared__ float qv_sh[256], ck_sh[256];
  int t = threadIdx.x;
  const float invN = 1.0f/(float)NROWS;
  float s0=0, sq0=0, s1=0, sq1=0;
  for (int r=0;r<8;r++){
    s0  += stats[r*1024 + t];       sq0 += stats[r*1024 + 256 + t];
    s1  += stats[r*1024 + 512 + t]; sq1 += stats[r*1024 + 768 + t];
  }
  {
    float mu = s0*invN, var = sq0*invN - mu*mu;
    float rs = rsqrtf(var + 1e-5f);
    float a = g0[t]*rs;
    prm[t] = a; prm[512+t] = be0[t] - mu*a;
  }
  {
    float mu = s1*invN, var = sq1*invN - mu*mu;
    float rs = rsqrtf(var + 1e-5f);
    float a = g1[t]*rs;
    prm[256+t] = a; prm[768+t] = be1[t] - mu*a;
  }
  float qs = inB[t];
  for (int k=0;k<256;k++) qs += inW[t*256 + k];
  qv_sh[t] = qs * 0.17677669529663689f;
  float cks = inB[256+t];
  for (int m=0;m<256;m++) cks += mergeB[m] * inW[(256+t)*256 + m];
  ck_sh[t] = cks;
  float cvs = inB[512+t];
  for (int m=0;m<256;m++) cvs += mergeB[m] * inW[(512+t)*256 + m];
  prm[1024+t] = cvs;
  float wf = 0;
  for (int m=0;m<256;m++) wf += rout[m] * outW[m*256 + t];
  prm[1288+t] = wf;
  __syncthreads();
  for (int r=0;r<8;r++){
    int idx = r*256 + t; int h = idx>>8, m = idx&255;
    float s = 0;
    for (int d=0;d<32;d++) s += qv_sh[h*32+d] * inW[(256 + h*32 + d)*256 + m];
    qk[h*256+m] = s;
  }
  if (t < 8){
    float cs_ = 0;
    for (int d=0;d<32;d++) cs_ += qv_sh[t*32+d]*ck_sh[t*32+d];
    prm[1280+t] = cs_;
  }
  if (t == 0){
    float cf = routB[0];
    for (int m=0;m<256;m++) cf += rout[m]*outB[m];
    prm[1544] = cf;
  }
}

// ---------------- Wall, PRE-TILED/PRE-SWIZZLED for gload_lds ----------------
// Layout: [step s(8)][2176-unit chunk]; unit c*8 + (u0 ^ (c&7)) holds Wall[c][k=s*64+u0*8..+7].
__global__ void k_wall(const float* __restrict__ inW, const float* __restrict__ mergeW,
                       const float* __restrict__ qk, short* __restrict__ Wall){
  int c = blockIdx.x; int t = threadIdx.x;  // 272 x 256
  float a0 = 0.f, a1 = 0.f;
  if (c < 264){
    const float* src = (c < 256) ? (inW + (512+c)*256) : (qk + (c-256)*256);
    for (int m=0;m<256;m++){
      float wm = src[m];
      a0 += wm * mergeW[m*512 + t];
      a1 += wm * mergeW[m*512 + 256 + t];
    }
  }
  int c7 = c & 7;
  int u1 = (t>>3) & 7, e1 = t & 7;
  int s1 = t >> 6;
  Wall[s1*17408 + (c*8 + (u1 ^ c7))*8 + e1] = f2bf_rne(a0);
  int s2 = 4 + (t >> 6);
  Wall[s2*17408 + (c*8 + (u1 ^ c7))*8 + e1] = f2bf_rne(a1);
}

// ---------------- fused BN+relu -> (v|scores) GEMM -> segment softmax-pool ----------------
// Block: 256 rows x 272 cols, K=512, BK=64 (8 steps), 8 waves (512 thr).
// LDS: h bf16 [256][64] (32KB) dbuf + Wall bf16 [272][64] (34KB) dbuf = 132KB.
// Wall staged via gload_lds from pre-tiled layout (278KB/block -> 222MB total, was 3.6GB).
// h reg-staged (T14): y loads issued before MFMAs, BN+relu+pack+ds_write after.
__global__ void __launch_bounds__(512)
k_fused(const short* __restrict__ y0, const short* __restrict__ y1,
        const short* __restrict__ Wall, const float* __restrict__ prm,
        float* __restrict__ num, float* __restrict__ den){
  __shared__ __align__(16) char lds[135168];
  int t = threadIdx.x, lane = t & 63, w = t >> 6;
  int l15 = lane & 15, q = lane >> 4;
  int gn0 = blockIdx.x << 8;
  int row0 = t >> 3, cu = t & 7;

  f32x4 acc[17][2];
  #pragma unroll
  for (int mt=0; mt<17; mt++){ acc[mt][0]=f32x4{0,0,0,0}; acc[mt][1]=f32x4{0,0,0,0}; }

  int4 yr0, yr1, yr2, yr3;
  f32x4 ca0, ca1, cb0, cb1;

  auto fload = [&](int s_){
    const short* ysel = (s_ < 4) ? y0 : y1;
    int kb = (s_ & 3) << 6;
    const short* rp = ysel + (size_t)(gn0 + row0)*256 + kb + (cu<<3);
    yr0 = *(const int4*)(rp);
    yr1 = *(const int4*)(rp +  64*256);
    yr2 = *(const int4*)(rp + 128*256);
    yr3 = *(const int4*)(rp + 192*256);
    int j = (s_<<6) + (cu<<3);
    ca0 = *(const f32x4*)(prm + j);        ca1 = *(const f32x4*)(prm + j + 4);
    cb0 = *(const f32x4*)(prm + 512 + j);  cb1 = *(const f32x4*)(prm + 512 + j + 4);
  };
  auto fwall = [&](int s_, int b_){
    const char* wg = (const char*)Wall + s_*34816;
    char* ld = lds + 65536 + b_*34816;
    #pragma unroll
    for (int i=0;i<4;i++)
      gl16(wg + ((i*512 + t)<<4), ld + ((i*512 + (w<<6))<<4));
    if (w < 2)
      gl16(wg + ((2048 + t)<<4), ld + ((2048 + (w<<6))<<4));
  };
  auto fwrite = [&](int b_){
    #pragma unroll
    for (int i=0;i<4;i++){
      int4 raw = (i==0)?yr0 : (i==1)?yr1 : (i==2)?yr2 : yr3;
      int row = (i<<6) + row0;
      unsigned r0=(unsigned)raw.x, r1=(unsigned)raw.y, r2=(unsigned)raw.z, r3=(unsigned)raw.w;
      float h0 = fmaxf(fmaf(bcf(r0<<16),         ca0[0], cb0[0]), 0.f);
      float h1 = fmaxf(fmaf(bcf(r0&0xffff0000u), ca0[1], cb0[1]), 0.f);
      float h2 = fmaxf(fmaf(bcf(r1<<16),         ca0[2], cb0[2]), 0.f);
      float h3 = fmaxf(fmaf(bcf(r1&0xffff0000u), ca0[3], cb0[3]), 0.f);
      float h4 = fmaxf(fmaf(bcf(r2<<16),         ca1[0], cb1[0]), 0.f);
      float h5 = fmaxf(fmaf(bcf(r2&0xffff0000u), ca1[1], cb1[1]), 0.f);
      float h6 = fmaxf(fmaf(bcf(r3<<16),         ca1[2], cb1[2]), 0.f);
      float h7 = fmaxf(fmaf(bcf(r3&0xffff0000u), ca1[3], cb1[3]), 0.f);
      int4 pk4; pk4.x=(int)pk_trunc(h0,h1); pk4.y=(int)pk_trunc(h2,h3);
                pk4.z=(int)pk_trunc(h4,h5); pk4.w=(int)pk_trunc(h6,h7);
      *(int4*)(lds + b_*32768 + (row<<7) + ((cu ^ (row&7))<<4)) = pk4;
    }
  };
  auto kstep = [&](int b_){
    int swz = (l15&7)<<4;
    #pragma unroll
    for (int ksub=0; ksub<2; ksub++){
      int ko = ((ksub<<2) + q) << 4;
      bf16x8 hx0, hx1;
      {
        int rowl = (w<<5) + l15;
        hx0 = *(const bf16x8*)(lds + b_*32768 + (((rowl<<7) + ko) ^ swz));
        hx1 = *(const bf16x8*)(lds + b_*32768 + ((((rowl+16)<<7) + ko) ^ swz));
      }
      const char* wp = lds + 65536 + b_*34816;
      #pragma unroll
      for (int mt=0; mt<17; mt++){
        int col = (mt<<4) + l15;
        bf16x8 wf = *(const bf16x8*)(wp + (((col<<7) + ko) ^ swz));
        acc[mt][0] = mfma16(wf, hx0, acc[mt][0]);
        acc[mt][1] = mfma16(wf, hx1, acc[mt][1]);
      }
    }
  };

  fload(0); fwall(0, 0); fwrite(0);
  __syncthreads();
  int buf = 0;
  #pragma unroll
  for (int s=0; s<8; s++){
    if (s < 7){ fload(s+1); fwall(s+1, buf^1); }
    kstep(buf);
    if (s < 7) fwrite(buf^1);
    __syncthreads();
    buf ^= 1;
  }

  // ---- epilogue: scores -> e -> den; v-tiles -> num (v4-verified) ----
  int nb = gn0 + (w<<5);
  f32x4 csv = *(const f32x4*)(prm + 1280 + q*4);
  float e0[4], e1[4];
  #pragma unroll
  for (int i=0;i<4;i++){
    e0[i] = (q<2) ? __expf(acc[16][0][i] + csv[i]) : 0.f;
    e1[i] = (q<2) ? __expf(acc[16][1][i] + csv[i]) : 0.f;
  }
  #pragma unroll
  for (int nt=0; nt<2; nt++){
    int tb = nb + nt*16;
    int sg = tb/100; int brow = (sg+1)*100 - tb; bool split = brow < 16;
    float d0[4], d1[4];
    #pragma unroll
    for (int i=0;i<4;i++){
      float ev = nt ? e1[i] : e0[i];
      d0[i] = (l15 < brow) ? ev : 0.f; d1[i] = ev - d0[i];
    }
    BFLY16(d0[0]); BFLY16(d0[1]); BFLY16(d0[2]); BFLY16(d0[3]);
    if (split){ BFLY16(d1[0]); BFLY16(d1[1]); BFLY16(d1[2]); BFLY16(d1[3]); }
    if (l15==0 && q<2){
      #pragma unroll
      for (int i=0;i<4;i++) atomicAdd(&den[sg*8 + q*4 + i], d0[i]);
      if (split){
        #pragma unroll
        for (int i=0;i<4;i++) atomicAdd(&den[(sg+1)*8 + q*4 + i], d1[i]);
      }
    }
  }
  #pragma unroll
  for (int mt=0; mt<16; mt++){
    const int h = mt>>1, hq = h>>2, hi = h&3;
    f32x4 cvv = *(const f32x4*)(prm + 1024 + mt*16 + q*4);
    #pragma unroll
    for (int nt=0; nt<2; nt++){
      float esrc = nt ? e1[hi] : e0[hi];
      float eb = __shfl(esrc, hq*16 + l15, 64);
      int tb = nb + nt*16;
      int sg = tb/100; int brow = (sg+1)*100 - tb; bool split = brow < 16;
      f32x4 accg = acc[mt][nt];
      float p0[4], p1[4];
      #pragma unroll
      for (int i=0;i<4;i++){
        float wv = (accg[i] + cvv[i]) * eb;
        p0[i] = (l15 < brow) ? wv : 0.f; p1[i] = wv - p0[i];
      }
      BFLY16(p0[0]); BFLY16(p0[1]); BFLY16(p0[2]); BFLY16(p0[3]);
      if (split){ BFLY16(p1[0]); BFLY16(p1[1]); BFLY16(p1[2]); BFLY16(p1[3]); }
      if (l15==0){
        int c0 = mt*16 + q*4;
        #pragma unroll
        for (int i=0;i<4;i++) atomicAdd(&num[sg*256 + c0 + i], p0[i]);
        if (split){
          #pragma unroll
          for (int i=0;i<4;i++) atomicAdd(&num[(sg+1)*256 + c0 + i], p1[i]);
        }
      }
    }
  }
}

// ---------------- final: out[g] = tanh(sum_c num/den * wfin + cfin) ----------------
__global__ void k_out(const float* __restrict__ num, const float* __restrict__ den,
                      const float* __restrict__ prm, float* __restrict__ out){
  int g = blockIdx.x; int lane = threadIdx.x; // 64
  f32x4 nm = *(const f32x4*)(num + g*256 + lane*4);
  f32x4 wf = *(const f32x4*)(prm + 1288 + lane*4);
  float dh = den[g*8 + (lane>>3)];
  float v = (nm[0]*wf[0] + nm[1]*wf[1] + nm[2]*wf[2] + nm[3]*wf[3]) / dh;
  v += __shfl_xor(v,1); v += __shfl_xor(v,2); v += __shfl_xor(v,4);
  v += __shfl_xor(v,8); v += __shfl_xor(v,16); v += __shfl_xor(v,32);
  if (lane==0) out[g] = tanhf(v + prm[1544]);
}

extern "C" void kernel_launch(void* const* d_in, const int* in_sizes, int n_in,
                              void* d_out, int out_size, void* d_ws, size_t ws_size,
                              hipStream_t stream){
  const float* x0      = (const float*)d_in[0];
  const float* x1      = (const float*)d_in[1];
  const float* p0_W    = (const float*)d_in[3];
  const float* p0_b    = (const float*)d_in[4];
  const float* p0_g    = (const float*)d_in[5];
  const float* p0_beta = (const float*)d_in[6];
  const float* p1_W    = (const float*)d_in[7];
  const float* p1_b    = (const float*)d_in[8];
  const float* p1_g    = (const float*)d_in[9];
  const float* p1_beta = (const float*)d_in[10];
  const float* merge_W = (const float*)d_in[11];
  const float* merge_b = (const float*)d_in[12];
  const float* inp_W   = (const float*)d_in[13];
  const float* inp_b   = (const float*)d_in[14];
  const float* out_W   = (const float*)d_in[15];
  const float* out_b   = (const float*)d_in[16];
  const float* ro_W    = (const float*)d_in[17];
  const float* ro_b    = (const float*)d_in[18];
  float* outp = (float*)d_out;

  char* ws = (char*)d_ws;
  short* y0w   = (short*)(ws);
  short* y1w   = (short*)(ws + 104857600);
  short* Wb    = (short*)(ws + 209715200);
  short* Wall  = (short*)(ws + 209977344);
  float* stats = (float*)(ws + 210255872);
  float* num   = (float*)(ws + 210288640);
  float* den   = (float*)(ws + 212385792);
  float* prm   = (float*)(ws + 212451328);
  float* qk    = (float*)(ws + 212459520);

  hipMemsetAsync(ws + 210255872, 0, 2195456, stream);   // stats + num + den

  k_cast_w<<<dim3(64), dim3(256), 0, stream>>>(p0_W, p1_W, Wb);
  k_gemm_y<<<dim3(2*NBLK_Y), dim3(256), 0, stream>>>(x0, x1, Wb, p0_b, p1_b, y0w, y1w, stats);
  k_small<<<dim3(1), dim3(256), 0, stream>>>(inp_W, inp_b, merge_b, p0_g, p0_beta, p1_g, p1_beta,
                                             out_W, out_b, ro_W, ro_b, stats, prm, qk);
  k_wall<<<dim3(272), dim3(256), 0, stream>>>(inp_W, merge_W, qk, Wall);
  k_fused<<<dim3(NBLK_F), dim3(512), 0, stream>>>(y0w, y1w, Wall, prm, num, den);
  k_out<<<dim3(GRP), dim3(64), 0, stream>>>(num, den, prm, outp);
}